// Round 12
// baseline (1084.788 us; speedup 1.0000x reference)
//
#include <hip/hip_runtime.h>

#define S_LEN 2048
#define DIN   50
#define H     64
#define XB    32
#define XPROWS (XB + 1)            // rows T .. T+32 (row 32 = next chunk's row 0)

// tanh(v) = 1 - 2/(exp(2v)+1); ~1e-6 rel err, exact at +/-inf
__device__ __forceinline__ float tanh_fast(float v) {
    float e = __builtin_amdgcn_exp2f(v * 2.885390082f);   // exp(2v)
    return 1.0f - 2.0f * __builtin_amdgcn_rcpf(e + 1.0f);
}

// Sum over the four 16-lane groups (every lane ends with the full sum).
// Proven on this toolchain (R3..R11 passed with absmax 0).
__device__ __forceinline__ float red4(float v) {
#if __has_builtin(__builtin_amdgcn_permlane16_swap) && __has_builtin(__builtin_amdgcn_permlane32_swap)
    typedef unsigned u2 __attribute__((ext_vector_type(2)));
    u2 r = __builtin_amdgcn_permlane16_swap(__float_as_uint(v), __float_as_uint(v), false, false);
    float s = __uint_as_float(r[0]) + __uint_as_float(r[1]);
    u2 q = __builtin_amdgcn_permlane32_swap(__float_as_uint(s), __float_as_uint(s), false, false);
    return __uint_as_float(q[0]) + __uint_as_float(q[1]);
#else
    v += __shfl_xor(v, 16, 64);
    v += __shfl_xor(v, 32, 64);
    return v;
#endif
}

__global__ __launch_bounds__(256)
__attribute__((amdgpu_waves_per_eu(2, 2)))   // 2048 waves = exactly 2/EU
void rnn_fused(const float* __restrict__ x,
               const float* __restrict__ W_ih0, const float* __restrict__ W_hh0,
               const float* __restrict__ b_ih0, const float* __restrict__ b_hh0,
               const float* __restrict__ W_ih1, const float* __restrict__ W_hh1,
               const float* __restrict__ b_ih1, const float* __restrict__ b_hh1,
               const float* __restrict__ W1, const float* __restrict__ b1,
               const float* __restrict__ W2, const float* __restrict__ b2,
               float* __restrict__ out)
{
    const int b    = blockIdx.x;
    const int tid  = threadIdx.x;
    const int lane = tid & 63;
    const int w    = tid >> 6;      // step loop: output chunk owner; refill: k-chunk owner
    const int j    = lane & 15;
    const int kg   = lane >> 4;     // 4-way k-split within wave
    const int outj = 16 * w + j;

    __shared__ __align__(16) float xraw[XPROWS][4][16];   // raw x rows, chunk-aligned
    __shared__ __align__(16) float xp4[XPROWS][H][4];     // xp k-partials (slot-permuted)
    __shared__ __align__(16) float h1s[2][H];             // h1[t] in h1s[t&1]
    __shared__ __align__(16) float h2s[2][H];             // h2[t] in h2s[t&1]

    // ---- per-lane weights, register-resident (61 floats total) ----
    float wxc[13];                     // W_ih0[lane][13w + i] — refill k-chunk only
    #pragma unroll
    for (int i = 0; i < 13; ++i) {
        int c = 13 * w + i;
        wxc[i] = (c < DIN) ? W_ih0[lane * DIN + c] : 0.0f;
    }
    const float bias0 = b_ih0[lane] + b_hh0[lane];   // folded into wave-0 partial

    float whh0_l[16], wih1_l[16], whh1_l[16];
    #pragma unroll
    for (int i = 0; i < 16; ++i) {
        whh0_l[i] = W_hh0[outj * H + 16 * kg + i];
        wih1_l[i] = W_ih1[outj * H + 16 * kg + i];
        whh1_l[i] = W_hh1[outj * H + 16 * kg + i];
    }
    const float bias1 = b_ih1[outj] + b_hh1[outj];

    const float* __restrict__ xrow = x + (size_t)b * (size_t)(S_LEN * DIN);

    // slot permutation spreads the 4 waves' partial-writes across banks;
    // the step-side b128 read sums all 4 slots (order-invariant).
    const int xslot = (w + (lane >> 2)) & 3;

    // ---- refill: stage 33 raw x rows; wave w writes its k-chunk partial of
    //      xp[u][h] = W_ih0[h].x[T+u] (+bias0 in wave 0) into xp4[u][h][slot] ----
    auto refill = [&](int T) {
        #pragma unroll
        for (int r = 0; r < 7; ++r) {                  // 7*256 = 1792 >= 33*52 = 1716
            int f = tid + 256 * r;
            if (f < XPROWS * 52) {
                int u   = f / 52;
                int rem = f - u * 52;
                int c   = rem / 13;
                int jj  = rem - 13 * c;
                int col = 13 * c + jj;
                int t   = T + u;
                float v = 0.0f;
                if (col < DIN && t < S_LEN) v = xrow[(size_t)t * DIN + col];
                xraw[u][c][jj] = v;
            }
        }
        __syncthreads();                               // xraw visible
        for (int u = 0; u < XPROWS; ++u) {
            const float4* xr = (const float4*)&xraw[u][w][0];   // wave-uniform bcast
            float4 A = xr[0], B = xr[1], C = xr[2];
            float  d = xraw[u][w][12];
            float a0 = (w == 0) ? bias0 : 0.0f, a1 = 0.0f;
            a0 = fmaf(A.x, wxc[0],  a0);  a1 = fmaf(A.y, wxc[1],  a1);
            a0 = fmaf(A.z, wxc[2],  a0);  a1 = fmaf(A.w, wxc[3],  a1);
            a0 = fmaf(B.x, wxc[4],  a0);  a1 = fmaf(B.y, wxc[5],  a1);
            a0 = fmaf(B.z, wxc[6],  a0);  a1 = fmaf(B.w, wxc[7],  a1);
            a0 = fmaf(C.x, wxc[8],  a0);  a1 = fmaf(C.y, wxc[9],  a1);
            a0 = fmaf(C.z, wxc[10], a0);  a1 = fmaf(C.w, wxc[11], a1);
            a0 = fmaf(d,   wxc[12], a0);
            xp4[u][lane][xslot] = a0 + a1;             // lane = hidden unit h
        }
        __syncthreads();                               // xp4 visible
    };

    float h1c[16], h2c[16];

    // ---- prologue: h1[0] = tanh(xp[0]); h2[-1] = 0 ----
    refill(0);
    {
        float4 p4 = *(const float4*)&xp4[0][outj][0];
        float h1n = tanh_fast((p4.x + p4.y) + (p4.z + p4.w));
        if (kg == 0) h1s[0][outj] = h1n;
        if (tid < 64) h2s[1][lane] = 0.0f;
    }
    __syncthreads();

    // One barrier interval I_t: given h1[t] (h1s[PAR]) and h2[t-1] (h2s[NPAR]),
    // compute h2[t] -> h2s[PAR] and h1[t+1] -> h1s[NPAR].  PAR = t&1 (literal).
    // XPIDX = (t-T)+1: xp row for h1[t+1].  xp is a FULL value: add after red4.
#define INTERVAL(PAR, NPAR, XPIDX)                                             \
    {                                                                          \
        *(float4*)&h1c[0]  = *(const float4*)&h1s[PAR][16 * kg + 0];           \
        *(float4*)&h1c[4]  = *(const float4*)&h1s[PAR][16 * kg + 4];           \
        *(float4*)&h1c[8]  = *(const float4*)&h1s[PAR][16 * kg + 8];           \
        *(float4*)&h1c[12] = *(const float4*)&h1s[PAR][16 * kg + 12];          \
        *(float4*)&h2c[0]  = *(const float4*)&h2s[NPAR][16 * kg + 0];          \
        *(float4*)&h2c[4]  = *(const float4*)&h2s[NPAR][16 * kg + 4];          \
        *(float4*)&h2c[8]  = *(const float4*)&h2s[NPAR][16 * kg + 8];          \
        *(float4*)&h2c[12] = *(const float4*)&h2s[NPAR][16 * kg + 12];         \
        float4 p4 = *(const float4*)&xp4[XPIDX][outj][0];                      \
        float xpn = (p4.x + p4.y) + (p4.z + p4.w);                             \
        /* stage 2: h2[t] = tanh(Wih1.h1[t] + Whh1.h2[t-1] + bias1) */         \
        float c0 = 0, c1 = 0, c2 = 0, c3 = 0;                                  \
        _Pragma("unroll")                                                      \
        for (int q = 0; q < 4; ++q) {                                          \
            c0 = fmaf(h1c[4 * q + 0], wih1_l[4 * q + 0], c0);                  \
            c1 = fmaf(h1c[4 * q + 1], wih1_l[4 * q + 1], c1);                  \
            c2 = fmaf(h1c[4 * q + 2], wih1_l[4 * q + 2], c2);                  \
            c3 = fmaf(h1c[4 * q + 3], wih1_l[4 * q + 3], c3);                  \
        }                                                                      \
        _Pragma("unroll")                                                      \
        for (int q = 0; q < 4; ++q) {                                          \
            c0 = fmaf(h2c[4 * q + 0], whh1_l[4 * q + 0], c0);                  \
            c1 = fmaf(h2c[4 * q + 1], whh1_l[4 * q + 1], c1);                  \
            c2 = fmaf(h2c[4 * q + 2], whh1_l[4 * q + 2], c2);                  \
            c3 = fmaf(h2c[4 * q + 3], whh1_l[4 * q + 3], c3);                  \
        }                                                                      \
        float h2n = tanh_fast(red4((c0 + c1) + (c2 + c3)) + bias1);            \
        /* stage 1: h1[t+1] = tanh(Whh0.h1[t] + xp[t+1]) */                    \
        float a0 = 0, a1 = 0, a2 = 0, a3 = 0;                                  \
        _Pragma("unroll")                                                      \
        for (int q = 0; q < 4; ++q) {                                          \
            a0 = fmaf(h1c[4 * q + 0], whh0_l[4 * q + 0], a0);                  \
            a1 = fmaf(h1c[4 * q + 1], whh0_l[4 * q + 1], a1);                  \
            a2 = fmaf(h1c[4 * q + 2], whh0_l[4 * q + 2], a2);                  \
            a3 = fmaf(h1c[4 * q + 3], whh0_l[4 * q + 3], a3);                  \
        }                                                                      \
        float h1n = tanh_fast(red4((a0 + a1) + (a2 + a3)) + xpn);              \
        if (kg == 0) {                                                         \
            h2s[PAR][outj]  = h2n;                                             \
            h1s[NPAR][outj] = h1n;                                             \
        }                                                                      \
        __syncthreads();                                                       \
    }

    for (int T = 0; T < S_LEN; T += XB) {
        if (T) refill(T);
        #pragma unroll
        for (int ui = 0; ui < XB; ui += 2) {
            INTERVAL(0, 1, ui + 1)       // t = T+ui   (even)
            INTERVAL(1, 0, ui + 2)       // t = T+ui+1 (odd)
        }
    }
#undef INTERVAL
    // (last interval's h1[2048] uses guarded xp[32] of the final chunk: loads
    //  were zero-guarded, value goes to h1s[0] and is never read)

    // ---- head: relu(h2 @ W1^T + b1) -> sigmoid(. @ W2^T + b2); h2[2047] in h2s[1] ----
    if (tid < 64) {
        float hv = 0.0f;
        if (lane < 32) {
            float acc = b1[lane];
            #pragma unroll
            for (int k = 0; k < H; ++k)
                acc = fmaf(h2s[1][k], W1[lane * H + k], acc);
            hv = fmaxf(acc, 0.0f) * W2[lane];
        }
        #pragma unroll
        for (int off = 32; off; off >>= 1)
            hv += __shfl_xor(hv, off, 64);
        if (lane == 0)
            out[b] = 1.0f / (1.0f + __expf(-(hv + b2[0])));
    }
}

extern "C" void kernel_launch(void* const* d_in, const int* in_sizes, int n_in,
                              void* d_out, int out_size, void* d_ws, size_t ws_size,
                              hipStream_t stream) {
    const float* x     = (const float*)d_in[0];
    const float* W_ih0 = (const float*)d_in[1];
    const float* W_hh0 = (const float*)d_in[2];
    const float* b_ih0 = (const float*)d_in[3];
    const float* b_hh0 = (const float*)d_in[4];
    const float* W_ih1 = (const float*)d_in[5];
    const float* W_hh1 = (const float*)d_in[6];
    const float* b_ih1 = (const float*)d_in[7];
    const float* b_hh1 = (const float*)d_in[8];
    const float* W1    = (const float*)d_in[9];
    const float* b1    = (const float*)d_in[10];
    const float* W2    = (const float*)d_in[11];
    const float* b2    = (const float*)d_in[12];
    float* out = (float*)d_out;

    rnn_fused<<<dim3(512), dim3(256), 0, stream>>>(
        x, W_ih0, W_hh0, b_ih0, b_hh0,
        W_ih1, W_hh1, b_ih1, b_hh1,
        W1, b1, W2, b2, out);
}

// Round 13
// 1079.257 us; speedup vs baseline: 1.0051x; 1.0051x over previous
//
#include <hip/hip_runtime.h>

#define S_LEN 2048
#define DIN   50
#define H     64
#define XB    32
#define XPROWS (XB + 1)            // rows T .. T+32 (row 32 = next chunk's row 0)

// tanh(v) = 1 - 2/(exp(2v)+1); ~1e-6 rel err, exact at +/-inf
__device__ __forceinline__ float tanh_fast(float v) {
    float e = __builtin_amdgcn_exp2f(v * 2.885390082f);   // exp(2v)
    return 1.0f - 2.0f * __builtin_amdgcn_rcpf(e + 1.0f);
}

// Sum over the four 16-lane groups (every lane ends with the full sum).
// Proven on this toolchain (R3..R12 passed with absmax 0).
__device__ __forceinline__ float red4(float v) {
#if __has_builtin(__builtin_amdgcn_permlane16_swap) && __has_builtin(__builtin_amdgcn_permlane32_swap)
    typedef unsigned u2 __attribute__((ext_vector_type(2)));
    u2 r = __builtin_amdgcn_permlane16_swap(__float_as_uint(v), __float_as_uint(v), false, false);
    float s = __uint_as_float(r[0]) + __uint_as_float(r[1]);
    u2 q = __builtin_amdgcn_permlane32_swap(__float_as_uint(s), __float_as_uint(s), false, false);
    return __uint_as_float(q[0]) + __uint_as_float(q[1]);
#else
    v += __shfl_xor(v, 16, 64);
    v += __shfl_xor(v, 32, 64);
    return v;
#endif
}

__global__ __launch_bounds__(256)
__attribute__((amdgpu_waves_per_eu(2, 2)))   // 2048 waves = exactly 2/EU
void rnn_fused(const float* __restrict__ x,
               const float* __restrict__ W_ih0, const float* __restrict__ W_hh0,
               const float* __restrict__ b_ih0, const float* __restrict__ b_hh0,
               const float* __restrict__ W_ih1, const float* __restrict__ W_hh1,
               const float* __restrict__ b_ih1, const float* __restrict__ b_hh1,
               const float* __restrict__ W1, const float* __restrict__ b1,
               const float* __restrict__ W2, const float* __restrict__ b2,
               float* __restrict__ out)
{
    const int b    = blockIdx.x;
    const int tid  = threadIdx.x;
    const int lane = tid & 63;
    const int w    = tid >> 6;      // step loop: output-chunk owner; refill: k-chunk owner
    const int j    = lane & 15;
    const int kg   = lane >> 4;     // 4-way k-split within wave
    const int outj = 16 * w + j;

    __shared__ __align__(16) float xraw[XPROWS][4][16];   // raw x rows, chunk-aligned
    __shared__ __align__(16) float xp4[XPROWS][4][64];    // xp k-partials, SLOT-MAJOR
    __shared__ __align__(16) float hst[4][H];             // [0]=h1s p0 [1]=h1s p1 [2]=h2s p0 [3]=h2s p1

    // ---- per-lane weights, register-resident (63 floats persistent) ----
    float wxc[13];                     // W_ih0[lane][13w + i] — refill k-chunk only
    #pragma unroll
    for (int i = 0; i < 13; ++i) {
        int c = 13 * w + i;
        wxc[i] = (c < DIN) ? W_ih0[lane * DIN + c] : 0.0f;
    }
    const float bias0 = b_ih0[lane] + b_hh0[lane];   // folded into wave-0 xp partial

    float whh0_l[16], wih1_l[16], whh1_l[16];
    #pragma unroll
    for (int i = 0; i < 16; ++i) {
        whh0_l[i] = W_hh0[outj * H + 16 * kg + i];
        wih1_l[i] = W_ih1[outj * H + 16 * kg + i];
        whh1_l[i] = W_hh1[outj * H + 16 * kg + i];
    }
    const float bias1 = b_ih1[outj] + b_hh1[outj];

    const float* __restrict__ xrow = x + (size_t)b * (size_t)(S_LEN * DIN);

    // single per-lane bases; all step-loop LDS ops = base + LITERAL offset
    const char* hrd = (const char*)&hst[0][0] + 64 * kg;    // reads: 16*kg floats in
    char*       hwr = (char*)&hst[0][0] + 4 * outj;         // writes (kg==0 lanes)
    const char* xrd = (const char*)&xp4[0][0][0] + 4 * outj;

    // ---- refill: stage 33 raw x rows; wave w writes k-chunk partial of
    //      xp[u][h] (+bias0 in wave 0) into xp4[u][w][h] (stride-1: conflict-free) ----
    auto refill = [&](int T) {
        #pragma unroll
        for (int r = 0; r < 7; ++r) {                  // 7*256 = 1792 >= 33*52 = 1716
            int f = tid + 256 * r;
            if (f < XPROWS * 52) {
                int u   = f / 52;
                int rem = f - u * 52;
                int c   = rem / 13;
                int jj  = rem - 13 * c;
                int col = 13 * c + jj;
                int t   = T + u;
                float v = 0.0f;
                if (col < DIN && t < S_LEN) v = xrow[(size_t)t * DIN + col];
                xraw[u][c][jj] = v;
            }
        }
        __syncthreads();                               // xraw visible
        for (int u = 0; u < XPROWS; ++u) {
            const float4* xr = (const float4*)&xraw[u][w][0];   // wave-uniform bcast
            float4 A = xr[0], B = xr[1], C = xr[2];
            float  d = xraw[u][w][12];
            float a0 = (w == 0) ? bias0 : 0.0f, a1 = 0.0f;
            a0 = fmaf(A.x, wxc[0],  a0);  a1 = fmaf(A.y, wxc[1],  a1);
            a0 = fmaf(A.z, wxc[2],  a0);  a1 = fmaf(A.w, wxc[3],  a1);
            a0 = fmaf(B.x, wxc[4],  a0);  a1 = fmaf(B.y, wxc[5],  a1);
            a0 = fmaf(B.z, wxc[6],  a0);  a1 = fmaf(B.w, wxc[7],  a1);
            a0 = fmaf(C.x, wxc[8],  a0);  a1 = fmaf(C.y, wxc[9],  a1);
            a0 = fmaf(C.z, wxc[10], a0);  a1 = fmaf(C.w, wxc[11], a1);
            a0 = fmaf(d,   wxc[12], a0);
            xp4[u][w][lane] = a0 + a1;
        }
        __syncthreads();                               // xp4 visible
    };

    float h1c[16], h2c[16];

    // ---- prologue: h1[0] = tanh(xp[0]); h2[-1] = 0 ----
    refill(0);
    {
        float p0 = *(const float*)(xrd + 0 * 256);
        float p1 = *(const float*)(xrd + 1 * 256);
        float p2 = *(const float*)(xrd + 2 * 256);
        float p3 = *(const float*)(xrd + 3 * 256);
        float h1n = tanh_fast((p0 + p1) + (p2 + p3));
        if (kg == 0) hst[0][outj] = h1n;
        if (tid < 64) hst[3][lane] = 0.0f;             // h2[-1] parity 1
    }
    __syncthreads();

    // Interval I_t: given h1[t] (hst[PAR]) and h2[t-1] (hst[2+NPAR]),
    // compute h2[t] -> hst[2+PAR] and h1[t+1] -> hst[NPAR].  PAR = t&1 literal.
    // XPIDX = (t-T)+1.  xp is a FULL value: added after red4.
#define INTERVAL(PAR, NPAR, XPIDX)                                             \
    {                                                                          \
        *(float4*)&h1c[0]  = *(const float4*)(hrd + (PAR)*256 + 0);            \
        *(float4*)&h1c[4]  = *(const float4*)(hrd + (PAR)*256 + 16);           \
        *(float4*)&h1c[8]  = *(const float4*)(hrd + (PAR)*256 + 32);           \
        *(float4*)&h1c[12] = *(const float4*)(hrd + (PAR)*256 + 48);           \
        *(float4*)&h2c[0]  = *(const float4*)(hrd + 512 + (NPAR)*256 + 0);     \
        *(float4*)&h2c[4]  = *(const float4*)(hrd + 512 + (NPAR)*256 + 16);    \
        *(float4*)&h2c[8]  = *(const float4*)(hrd + 512 + (NPAR)*256 + 32);    \
        *(float4*)&h2c[12] = *(const float4*)(hrd + 512 + (NPAR)*256 + 48);    \
        float p0 = *(const float*)(xrd + (XPIDX)*1024 + 0 * 256);              \
        float p1 = *(const float*)(xrd + (XPIDX)*1024 + 1 * 256);              \
        float p2 = *(const float*)(xrd + (XPIDX)*1024 + 2 * 256);              \
        float p3 = *(const float*)(xrd + (XPIDX)*1024 + 3 * 256);              \
        float xpn = (p0 + p1) + (p2 + p3);                                     \
        /* stage 2: h2[t] = tanh(Wih1.h1[t] + Whh1.h2[t-1] + bias1) */         \
        float cA0 = 0, cA1 = 0, cA2 = 0, cA3 = 0;                              \
        float cB0 = 0, cB1 = 0, cB2 = 0, cB3 = 0;                              \
        _Pragma("unroll")                                                      \
        for (int q = 0; q < 4; ++q) {                                          \
            cA0 = fmaf(h1c[4 * q + 0], wih1_l[4 * q + 0], cA0);                \
            cA1 = fmaf(h1c[4 * q + 1], wih1_l[4 * q + 1], cA1);                \
            cA2 = fmaf(h1c[4 * q + 2], wih1_l[4 * q + 2], cA2);                \
            cA3 = fmaf(h1c[4 * q + 3], wih1_l[4 * q + 3], cA3);                \
        }                                                                      \
        _Pragma("unroll")                                                      \
        for (int q = 0; q < 4; ++q) {                                          \
            cB0 = fmaf(h2c[4 * q + 0], whh1_l[4 * q + 0], cB0);                \
            cB1 = fmaf(h2c[4 * q + 1], whh1_l[4 * q + 1], cB1);                \
            cB2 = fmaf(h2c[4 * q + 2], whh1_l[4 * q + 2], cB2);                \
            cB3 = fmaf(h2c[4 * q + 3], whh1_l[4 * q + 3], cB3);                \
        }                                                                      \
        float csum = ((cA0 + cA1) + (cA2 + cA3)) + ((cB0 + cB1) + (cB2 + cB3));\
        float h2n = tanh_fast(red4(csum) + bias1);                             \
        /* stage 1: h1[t+1] = tanh(Whh0.h1[t] + xp[t+1]) */                    \
        float a0 = 0, a1 = 0, a2 = 0, a3 = 0;                                  \
        _Pragma("unroll")                                                      \
        for (int q = 0; q < 4; ++q) {                                          \
            a0 = fmaf(h1c[4 * q + 0], whh0_l[4 * q + 0], a0);                  \
            a1 = fmaf(h1c[4 * q + 1], whh0_l[4 * q + 1], a1);                  \
            a2 = fmaf(h1c[4 * q + 2], whh0_l[4 * q + 2], a2);                  \
            a3 = fmaf(h1c[4 * q + 3], whh0_l[4 * q + 3], a3);                  \
        }                                                                      \
        float h1n = tanh_fast(red4((a0 + a1) + (a2 + a3)) + xpn);              \
        if (kg == 0) {                                                         \
            *(float*)(hwr + 512 + (PAR)*256) = h2n;                            \
            *(float*)(hwr + (NPAR)*256)      = h1n;                            \
        }                                                                      \
        __syncthreads();                                                       \
    }

    for (int T = 0; T < S_LEN; T += XB) {
        if (T) refill(T);
        #pragma unroll
        for (int ui = 0; ui < XB; ui += 2) {
            INTERVAL(0, 1, ui + 1)       // t = T+ui   (even)
            INTERVAL(1, 0, ui + 2)       // t = T+ui+1 (odd)
        }
    }
#undef INTERVAL
    // (last interval's h1[2048] uses guarded xp[32] of the final chunk: loads
    //  were zero-guarded, value goes to hst[0] and is never read)

    // ---- head: relu(h2 @ W1^T + b1) -> sigmoid(. @ W2^T + b2); h2[2047] in hst[3] ----
    if (tid < 64) {
        float hv = 0.0f;
        if (lane < 32) {
            float acc = b1[lane];
            #pragma unroll
            for (int k = 0; k < H; ++k)
                acc = fmaf(hst[3][k], W1[lane * H + k], acc);
            hv = fmaxf(acc, 0.0f) * W2[lane];
        }
        #pragma unroll
        for (int off = 32; off; off >>= 1)
            hv += __shfl_xor(hv, off, 64);
        if (lane == 0)
            out[b] = 1.0f / (1.0f + __expf(-(hv + b2[0])));
    }
}

extern "C" void kernel_launch(void* const* d_in, const int* in_sizes, int n_in,
                              void* d_out, int out_size, void* d_ws, size_t ws_size,
                              hipStream_t stream) {
    const float* x     = (const float*)d_in[0];
    const float* W_ih0 = (const float*)d_in[1];
    const float* W_hh0 = (const float*)d_in[2];
    const float* b_ih0 = (const float*)d_in[3];
    const float* b_hh0 = (const float*)d_in[4];
    const float* W_ih1 = (const float*)d_in[5];
    const float* W_hh1 = (const float*)d_in[6];
    const float* b_ih1 = (const float*)d_in[7];
    const float* b_hh1 = (const float*)d_in[8];
    const float* W1    = (const float*)d_in[9];
    const float* b1    = (const float*)d_in[10];
    const float* W2    = (const float*)d_in[11];
    const float* b2    = (const float*)d_in[12];
    float* out = (float*)d_out;

    rnn_fused<<<dim3(512), dim3(256), 0, stream>>>(
        x, W_ih0, W_hh0, b_ih0, b_hh0,
        W_ih1, W_hh1, b_ih1, b_hh1,
        W1, b1, W2, b2, out);
}